// Round 1
// baseline (1280.716 us; speedup 1.0000x reference)
//
#include <hip/hip_runtime.h>
#include <stdint.h>

#define VOCAB 32000
#define HID   512
#define NBAT  32
#define NSRC  128
#define NTGT  64

typedef __attribute__((ext_vector_type(8))) __bf16 bf16x8;
typedef __attribute__((ext_vector_type(4))) float  f32x4;

__device__ __forceinline__ ushort f2bf(float f) {
  union { float f; uint32_t u; } v; v.f = f;
  uint32_t u = v.u;
  u += 0x7fffu + ((u >> 16) & 1u);
  return (ushort)(u >> 16);
}

__device__ __forceinline__ float sigmoidf_(float x) { return 1.0f / (1.0f + expf(-x)); }

__device__ __forceinline__ int swz(int row, int chunk16) {
  return (chunk16 * 16) ^ ((row & 7) * 16);
}

__device__ __forceinline__ f32x4 mfma16(bf16x8 a, bf16x8 b, f32x4 c) {
  return __builtin_amdgcn_mfma_f32_16x16x32_bf16(a, b, c, 0, 0, 0);
}

// ---------------------------------------------------------------- utilities
__global__ void init_kernel(const int* __restrict__ trg, int* __restrict__ tok_in,
                            const float* __restrict__ b_ih, const float* __restrict__ b_hh,
                            float* __restrict__ bsum, int* __restrict__ cnt) {
  int i = blockIdx.x * 256 + threadIdx.x;
  if (i < 2048) {
    int t = i >> 5, b = i & 31;
    tok_in[i] = (t == 0) ? 0 : trg[b * NTGT + (t - 1)];
    bsum[i] = b_ih[i] + b_hh[i];
  }
  if (i == 0) *cnt = 0;
}

__global__ void cvt_kernel(const float* __restrict__ src, ushort* __restrict__ dst, int n4) {
  int i = blockIdx.x * 256 + threadIdx.x;
  if (i < n4) {
    float4 v = reinterpret_cast<const float4*>(src)[i];
    ushort4 o;
    o.x = f2bf(v.x); o.y = f2bf(v.y); o.z = f2bf(v.z); o.w = f2bf(v.w);
    reinterpret_cast<ushort4*>(dst)[i] = o;
  }
}

// ---------------------------------------------------------------- bridge
__global__ __launch_bounds__(256, 2)
void bridge_kernel(const float* __restrict__ init_hidden, const float* __restrict__ bW,
                   const float* __restrict__ bb, float* __restrict__ hbuf_f32,
                   ushort* __restrict__ hbuf_bf) {
  __shared__ float ih[512];
  int b = blockIdx.x, tid = threadIdx.x;
  ih[tid] = init_hidden[b * 512 + tid];
  ih[tid + 256] = init_hidden[b * 512 + 256 + tid];
  __syncthreads();
  for (int rep = 0; rep < 2; ++rep) {
    int j = tid + rep * 256;
    const float4* wr = reinterpret_cast<const float4*>(bW + (size_t)j * 512);
    float s = 0.0f;
    #pragma unroll 4
    for (int k = 0; k < 128; ++k) {
      float4 wv = wr[k];
      s += wv.x * ih[k*4] + wv.y * ih[k*4+1] + wv.z * ih[k*4+2] + wv.w * ih[k*4+3];
    }
    float v = tanhf(s + bb[j]);
    hbuf_f32[b * 512 + j] = v;
    hbuf_bf[b * 512 + j]  = f2bf(v);
  }
}

// ---------------------------------------------------------------- generic GEMM C = A(f32->bf16) * Bw(bf16)^T + bias
// tiles: 128x128, BK=64, 4 waves, 16x16x32 MFMA. A row-major [M][K]; Bw row-major [N][K].
template<int GATHER, int TANH>
__global__ __launch_bounds__(256, 2)
void gemm_bt(const float* __restrict__ A, const ushort* __restrict__ Bw,
             const float* __restrict__ bias, float* __restrict__ C,
             const int* __restrict__ gidx, int N, int K) {
  __shared__ __align__(16) char smem[32768];
  char* smA = smem;
  char* smB = smem + 16384;
  const int tid = threadIdx.x;
  const int w = tid >> 6, l = tid & 63;
  const int m0 = blockIdx.x * 128, n0 = blockIdx.y * 128;
  const int msub = (w & 1) * 64, nsub = (w >> 1) * 64;

  f32x4 acc[4][4] = {};
  const int kiters = K >> 6;
  for (int ki = 0; ki < kiters; ++ki) {
    __syncthreads();
    // stage A: 128 x 64 f32 -> bf16
    #pragma unroll
    for (int c = 0; c < 8; ++c) {
      int id = tid + c * 256;
      int row = id >> 4, f4 = id & 15;
      int arow = GATHER ? gidx[m0 + row] : (m0 + row);
      float4 av = *reinterpret_cast<const float4*>(A + (size_t)arow * K + ki * 64 + f4 * 4);
      uint32_t lo = (uint32_t)f2bf(av.x) | ((uint32_t)f2bf(av.y) << 16);
      uint32_t hi = (uint32_t)f2bf(av.z) | ((uint32_t)f2bf(av.w) << 16);
      int byte = row * 128 + swz(row, f4 >> 1) + (f4 & 1) * 8;
      *reinterpret_cast<uint2*>(smA + byte) = make_uint2(lo, hi);
    }
    // stage B: 128 x 64 bf16
    #pragma unroll
    for (int c = 0; c < 4; ++c) {
      int id = tid + c * 256;
      int row = id >> 3, kc = id & 7;
      uint4 bv = *reinterpret_cast<const uint4*>(Bw + (size_t)(n0 + row) * K + ki * 64 + kc * 8);
      int byte = row * 128 + swz(row, kc);
      *reinterpret_cast<uint4*>(smB + byte) = bv;
    }
    __syncthreads();
    #pragma unroll
    for (int ks = 0; ks < 2; ++ks) {
      bf16x8 af[4], bfr[4];
      #pragma unroll
      for (int i = 0; i < 4; ++i) {
        int row = msub + i * 16 + (l & 15);
        af[i] = *reinterpret_cast<const bf16x8*>(smA + row * 128 + swz(row, ks * 4 + (l >> 4)));
      }
      #pragma unroll
      for (int i = 0; i < 4; ++i) {
        int row = nsub + i * 16 + (l & 15);
        bfr[i] = *reinterpret_cast<const bf16x8*>(smB + row * 128 + swz(row, ks * 4 + (l >> 4)));
      }
      #pragma unroll
      for (int mi = 0; mi < 4; ++mi)
        #pragma unroll
        for (int ni = 0; ni < 4; ++ni)
          acc[mi][ni] = mfma16(af[mi], bfr[ni], acc[mi][ni]);
    }
  }
  #pragma unroll
  for (int mi = 0; mi < 4; ++mi) {
    #pragma unroll
    for (int ni = 0; ni < 4; ++ni) {
      int col = n0 + nsub + ni * 16 + (l & 15);
      float bb = bias ? bias[col] : 0.0f;
      #pragma unroll
      for (int j = 0; j < 4; ++j) {
        int row = m0 + msub + mi * 16 + (l >> 4) * 4 + j;
        float v = acc[mi][ni][j] + bb;
        if (TANH) v = tanhf(v);
        C[(size_t)row * N + col] = v;
      }
    }
  }
}

// ---------------------------------------------------------------- LSTM recurrence (persistent, 32 blocks, global barrier per step)
__global__ __launch_bounds__(256, 1)
void lstm_rec(const ushort* __restrict__ Whh_bf, const float* __restrict__ gates_x,
              float* __restrict__ hbuf_f32, ushort* __restrict__ hbuf_bf,
              int* __restrict__ cnt) {
  __shared__ __align__(16) char h_lds[32 * 1024];   // [32][512] bf16, swizzled rows
  __shared__ float gt[32 * 64];
  __shared__ float c_state[512];
  const int tid = threadIdx.x, w = tid >> 6, l = tid & 63;
  const int blk = blockIdx.x;          // 0..31, owns h-cols [blk*16, blk*16+16)
  const int gate0 = (w >> 1) * 2;      // waves 0,1 -> gates {i,f}; waves 2,3 -> {g,o}
  const int mtile = (w & 1);           // waves 0,2 -> b 0..15; waves 1,3 -> b 16..31

  // W_hh fragments held in registers for the whole kernel
  bf16x8 wf[2][16];
  #pragma unroll
  for (int nt = 0; nt < 2; ++nt) {
    int grow = (gate0 + nt) * 512 + blk * 16 + (l & 15);
    const ushort* base = Whh_bf + (size_t)grow * 512 + (l >> 4) * 8;
    #pragma unroll
    for (int ks = 0; ks < 16; ++ks)
      wf[nt][ks] = *reinterpret_cast<const bf16x8*>(base + ks * 32);
  }

  for (int idx = tid; idx < 512; idx += 256) {
    int b = idx >> 4, cc = idx & 15;
    c_state[idx] = hbuf_f32[b * 512 + blk * 16 + cc];   // c0 = h0
  }

  for (int t = 0; t < NTGT; ++t) {
    // stage h_{t} (bf16) into LDS
    const ushort* hsrc = hbuf_bf + (size_t)t * (32 * 512);
    #pragma unroll
    for (int c = 0; c < 8; ++c) {
      int id = tid + c * 256;
      int row = id >> 6, ch = id & 63;
      uint4 v = *reinterpret_cast<const uint4*>(hsrc + row * 512 + ch * 8);
      *reinterpret_cast<uint4*>(h_lds + row * 1024 + ((ch * 16) ^ ((row & 7) * 16))) = v;
    }
    __syncthreads();

    f32x4 acc[2];
    #pragma unroll
    for (int nt = 0; nt < 2; ++nt) {
      #pragma unroll
      for (int j = 0; j < 4; ++j) {
        int b = mtile * 16 + (l >> 4) * 4 + j;
        acc[nt][j] = gates_x[(size_t)(t * 32 + b) * 2048 + (gate0 + nt) * 512 + blk * 16 + (l & 15)];
      }
    }
    #pragma unroll
    for (int ks = 0; ks < 16; ++ks) {
      int row = mtile * 16 + (l & 15);
      bf16x8 af = *reinterpret_cast<const bf16x8*>(
          h_lds + row * 1024 + (((ks * 4 + (l >> 4)) * 16) ^ ((row & 7) * 16)));
      acc[0] = mfma16(af, wf[0][ks], acc[0]);
      acc[1] = mfma16(af, wf[1][ks], acc[1]);
    }
    #pragma unroll
    for (int nt = 0; nt < 2; ++nt)
      #pragma unroll
      for (int j = 0; j < 4; ++j) {
        int b = mtile * 16 + (l >> 4) * 4 + j;
        gt[b * 64 + (gate0 + nt) * 16 + (l & 15)] = acc[nt][j];
      }
    __syncthreads();

    #pragma unroll
    for (int rep = 0; rep < 2; ++rep) {
      int idx = tid + rep * 256;
      int b = idx >> 4, cc = idx & 15;
      float gi = gt[b * 64 + cc],      gf = gt[b * 64 + 16 + cc];
      float gg = gt[b * 64 + 32 + cc], go = gt[b * 64 + 48 + cc];
      float cn = sigmoidf_(gf) * c_state[idx] + sigmoidf_(gi) * tanhf(gg);
      float hn = sigmoidf_(go) * tanhf(cn);
      c_state[idx] = cn;
      size_t o = (size_t)(t + 1) * (32 * 512) + b * 512 + blk * 16 + cc;
      hbuf_f32[o] = hn;
      hbuf_bf[o]  = f2bf(hn);
    }
    __threadfence();
    __syncthreads();
    if (tid == 0) {
      __hip_atomic_fetch_add(cnt, 1, __ATOMIC_ACQ_REL, __HIP_MEMORY_SCOPE_AGENT);
      int target = 32 * (t + 1);
      while (__hip_atomic_load(cnt, __ATOMIC_ACQUIRE, __HIP_MEMORY_SCOPE_AGENT) < target)
        __builtin_amdgcn_s_sleep(2);
    }
    __syncthreads();
  }
}

// ---------------------------------------------------------------- per-row stats: gen max/sumexp + copy scores
__global__ __launch_bounds__(256, 2)
void stats_kernel(const float* __restrict__ sg, const float* __restrict__ hbuf_f32,
                  const float* __restrict__ u_feat, float* __restrict__ ue_out,
                  float4* __restrict__ stats) {
  __shared__ float red[256];
  __shared__ float hl[512];
  __shared__ float up[256];
  int r = blockIdx.x, tid = threadIdx.x;
  int t = r >> 5, b = r & 31;
  const float* row = sg + (size_t)r * VOCAB;
  float m = -3.0e38f;
  for (int i = 0; i < 125; ++i) m = fmaxf(m, row[tid + i * 256]);
  red[tid] = m; __syncthreads();
  for (int s = 128; s > 0; s >>= 1) { if (tid < s) red[tid] = fmaxf(red[tid], red[tid + s]); __syncthreads(); }
  float G = red[0]; __syncthreads();
  float ssum = 0.0f;
  for (int i = 0; i < 125; ++i) ssum += expf(row[tid + i * 256] - G);
  red[tid] = ssum; __syncthreads();
  for (int s = 128; s > 0; s >>= 1) { if (tid < s) red[tid] += red[tid + s]; __syncthreads(); }
  float Sg = red[0]; __syncthreads();

  const float* hrow = hbuf_f32 + (size_t)(t + 1) * (32 * 512) + b * 512;
  hl[tid] = hrow[tid]; hl[tid + 256] = hrow[tid + 256];
  __syncthreads();
  {
    int s = tid & 127, half = tid >> 7;
    const float4* uf = reinterpret_cast<const float4*>(u_feat + (size_t)(s * 32 + b) * 512 + half * 256);
    const float* hh = hl + half * 256;
    float p = 0.0f;
    #pragma unroll 4
    for (int k = 0; k < 64; ++k) {
      float4 v = uf[k];
      p += v.x * hh[k*4] + v.y * hh[k*4+1] + v.z * hh[k*4+2] + v.w * hh[k*4+3];
    }
    up[tid] = p;
  }
  __syncthreads();
  float u = 0.0f;
  if (tid < 128) u = up[tid] + up[tid + 128];
  red[tid] = (tid < 128) ? u : -3.0e38f;
  __syncthreads();
  for (int s = 128; s > 0; s >>= 1) { if (tid < s) red[tid] = fmaxf(red[tid], red[tid + s]); __syncthreads(); }
  float umax = red[0]; __syncthreads();
  float uev = 0.0f;
  if (tid < 128) { uev = expf(u - umax); ue_out[(size_t)r * 128 + tid] = uev; }
  red[tid] = (tid < 128) ? uev : 0.0f;
  __syncthreads();
  for (int s = 128; s > 0; s >>= 1) { if (tid < s) red[tid] += red[tid + s]; __syncthreads(); }
  if (tid == 0) {
    float Sue = red[0];
    float M = fmaxf(G, umax);
    float Z = Sg * expf(G - M) + expf(umax - M) * (Sue + (float)VOCAB * 1e-35f);
    stats[r] = make_float4(M, logf(Z), expf(umax - M), 0.0f);
  }
}

// ---------------------------------------------------------------- dense log transform (in place)
__global__ __launch_bounds__(256, 4)
void transform_kernel(float* __restrict__ out, const float4* __restrict__ stats) {
  int r = blockIdx.x, tid = threadIdx.x;
  float4 st = stats[r];
  float M = st.x, logZ = st.y, c0 = st.z * 1e-35f;
  float4* row = reinterpret_cast<float4*>(out + (size_t)r * VOCAB);
  for (int i = 0; i < 32; ++i) {
    int idx = i * 256 + tid;
    if (idx < 8000) {
      float4 x = row[idx];
      x.x = logf(expf(x.x - M) + c0) - logZ;
      x.y = logf(expf(x.y - M) + c0) - logZ;
      x.z = logf(expf(x.z - M) + c0) - logZ;
      x.w = logf(expf(x.w - M) + c0) - logZ;
      row[idx] = x;
    }
  }
}

// ---------------------------------------------------------------- scattered-position fixup
__global__ __launch_bounds__(128, 4)
void fixup_kernel(float* __restrict__ out, const float* __restrict__ hbuf_f32,
                  const float* __restrict__ ue, const int* __restrict__ enc_idxs,
                  const float* __restrict__ outW, const float* __restrict__ outb,
                  const float4* __restrict__ stats) {
  __shared__ float hl[512];
  __shared__ float uel[128];
  __shared__ int il[128];
  int r = blockIdx.x, tid = threadIdx.x;
  int t = r >> 5, b = r & 31;
  const float* hrow = hbuf_f32 + (size_t)(t + 1) * (32 * 512) + b * 512;
  for (int i = tid; i < 512; i += 128) hl[i] = hrow[i];
  uel[tid] = ue[(size_t)r * 128 + tid];
  il[tid]  = enc_idxs[b * NSRC + tid];
  __syncthreads();
  int v = il[tid];
  float scat = 0.0f;
  #pragma unroll 8
  for (int s = 0; s < 128; ++s) scat += (il[s] == v) ? uel[s] : 0.0f;
  const float4* wr = reinterpret_cast<const float4*>(outW + (size_t)v * 512);
  const float4* hf = reinterpret_cast<const float4*>(hl);
  float p = 0.0f;
  #pragma unroll 4
  for (int k = 0; k < 128; ++k) {
    float4 wv = wr[k]; float4 hv = hf[k];
    p += wv.x * hv.x + wv.y * hv.y + wv.z * hv.z + wv.w * hv.w;
  }
  p += outb[v];
  float4 st = stats[r];
  float val = logf(expf(p - st.x) + st.z * (scat + 1e-35f)) - st.y;
  out[(size_t)r * VOCAB + v] = val;
}

// ---------------------------------------------------------------- launch
extern "C" void kernel_launch(void* const* d_in, const int* in_sizes, int n_in,
                              void* d_out, int out_size, void* d_ws, size_t ws_size,
                              hipStream_t stream) {
  (void)in_sizes; (void)n_in; (void)out_size; (void)ws_size;
  const int*   trg      = (const int*)  d_in[0];
  const float* init_h   = (const float*)d_in[1];
  const float* enc_hs   = (const float*)d_in[2];
  const int*   enc_idxs = (const int*)  d_in[3];
  const float* emb      = (const float*)d_in[4];
  const float* W_ih     = (const float*)d_in[5];
  const float* W_hh     = (const float*)d_in[6];
  const float* b_ih     = (const float*)d_in[7];
  const float* b_hh     = (const float*)d_in[8];
  const float* bridge_W = (const float*)d_in[9];
  const float* bridge_b = (const float*)d_in[10];
  const float* out_W    = (const float*)d_in[11];
  const float* out_b    = (const float*)d_in[12];
  const float* copy_W   = (const float*)d_in[13];
  const float* copy_b   = (const float*)d_in[14];
  float* out = (float*)d_out;

  char* ws = (char*)d_ws;
  size_t off = 0;
  auto alloc = [&](size_t bytes) -> char* {
    char* p = ws + off;
    off = (off + bytes + 255) & ~(size_t)255;
    return p;
  };
  ushort* outW_bf  = (ushort*)alloc((size_t)VOCAB * 512 * 2);
  ushort* Wih_bf   = (ushort*)alloc((size_t)2048 * 512 * 2);
  ushort* copyW_bf = (ushort*)alloc((size_t)512 * 512 * 2);
  ushort* Whh_bf   = (ushort*)alloc((size_t)2048 * 512 * 2);
  float*  u_feat   = (float*) alloc((size_t)NSRC * NBAT * 512 * 4);
  float*  gates_x  = (float*) alloc((size_t)NTGT * NBAT * 2048 * 4);
  float*  hbuf_f32 = (float*) alloc((size_t)(NTGT + 1) * NBAT * 512 * 4);
  ushort* hbuf_bf  = (ushort*)alloc((size_t)(NTGT + 1) * NBAT * 512 * 2);
  float*  ue       = (float*) alloc((size_t)2048 * 128 * 4);
  float4* stats    = (float4*)alloc((size_t)2048 * 16);
  int*    tok_in   = (int*)   alloc(2048 * 4);
  float*  bsum     = (float*) alloc(2048 * 4);
  int*    cnt      = (int*)   alloc(256);

  init_kernel<<<8, 256, 0, stream>>>(trg, tok_in, b_ih, b_hh, bsum, cnt);
  cvt_kernel<<<(VOCAB * 512 / 4 + 255) / 256, 256, 0, stream>>>(out_W, outW_bf, VOCAB * 512 / 4);
  cvt_kernel<<<(2048 * 512 / 4 + 255) / 256, 256, 0, stream>>>(W_ih, Wih_bf, 2048 * 512 / 4);
  cvt_kernel<<<(512 * 512 / 4 + 255) / 256, 256, 0, stream>>>(copy_W, copyW_bf, 512 * 512 / 4);
  cvt_kernel<<<(2048 * 512 / 4 + 255) / 256, 256, 0, stream>>>(W_hh, Whh_bf, 2048 * 512 / 4);

  bridge_kernel<<<32, 256, 0, stream>>>(init_h, bridge_W, bridge_b, hbuf_f32, hbuf_bf);
  // u_feat[s,b,h] = tanh(enc_hs[s,b,:] . copy_W[h,:] + copy_b[h])
  gemm_bt<0, 1><<<dim3(32, 4), 256, 0, stream>>>(enc_hs, copyW_bf, copy_b, u_feat, nullptr, 512, 512);
  // gates_x[t,b,:] = emb[tok_in[t,b]] . W_ih^T + b_ih + b_hh
  gemm_bt<1, 0><<<dim3(16, 16), 256, 0, stream>>>(emb, Wih_bf, bsum, gates_x, tok_in, 2048, 512);
  lstm_rec<<<32, 256, 0, stream>>>(Whh_bf, gates_x, hbuf_f32, hbuf_bf, cnt);
  // sg[t*32+b, v] = h[t,b,:] . out_W[v,:] + out_b[v]   (written into d_out as scratch)
  gemm_bt<0, 0><<<dim3(16, 250), 256, 0, stream>>>(hbuf_f32 + 32 * 512, outW_bf, out_b, out, nullptr, VOCAB, 512);
  stats_kernel<<<2048, 256, 0, stream>>>(out, hbuf_f32, u_feat, ue, stats);
  transform_kernel<<<2048, 256, 0, stream>>>(out, stats);
  fixup_kernel<<<2048, 128, 0, stream>>>(out, hbuf_f32, ue, enc_idxs, out_W, out_b, stats);
}

// Round 2
// 1005.183 us; speedup vs baseline: 1.2741x; 1.2741x over previous
//
#include <hip/hip_runtime.h>
#include <stdint.h>

#define VOCAB 32000
#define HID   512
#define NBAT  32
#define NSRC  128
#define NTGT  64

typedef __attribute__((ext_vector_type(8))) __bf16 bf16x8;
typedef __attribute__((ext_vector_type(4))) float  f32x4;

__device__ __forceinline__ ushort f2bf(float f) {
  union { float f; uint32_t u; } v; v.f = f;
  uint32_t u = v.u;
  u += 0x7fffu + ((u >> 16) & 1u);
  return (ushort)(u >> 16);
}

__device__ __forceinline__ float sigmoidf_(float x) { return 1.0f / (1.0f + expf(-x)); }

__device__ __forceinline__ int swz(int row, int chunk16) {
  return (chunk16 * 16) ^ ((row & 7) * 16);
}

__device__ __forceinline__ f32x4 mfma16(bf16x8 a, bf16x8 b, f32x4 c) {
  return __builtin_amdgcn_mfma_f32_16x16x32_bf16(a, b, c, 0, 0, 0);
}

// ---------------------------------------------------------------- utilities
__global__ void init_kernel(const int* __restrict__ trg, int* __restrict__ tok_in,
                            const float* __restrict__ b_ih, const float* __restrict__ b_hh,
                            float* __restrict__ bsum, int* __restrict__ flags) {
  int i = blockIdx.x * 256 + threadIdx.x;
  if (i < 2048) {
    int t = i >> 5, b = i & 31;
    tok_in[i] = (t == 0) ? 0 : trg[b * NTGT + (t - 1)];
    bsum[i] = b_ih[i] + b_hh[i];
  }
  if (i < 1024) flags[i] = 0;   // 32 flags, one per 128B line (stride 32 ints)
}

__global__ void cvt_kernel(const float* __restrict__ src, ushort* __restrict__ dst, int n4) {
  int i = blockIdx.x * 256 + threadIdx.x;
  if (i < n4) {
    float4 v = reinterpret_cast<const float4*>(src)[i];
    ushort4 o;
    o.x = f2bf(v.x); o.y = f2bf(v.y); o.z = f2bf(v.z); o.w = f2bf(v.w);
    reinterpret_cast<ushort4*>(dst)[i] = o;
  }
}

// ---------------------------------------------------------------- bridge
__global__ __launch_bounds__(256, 2)
void bridge_kernel(const float* __restrict__ init_hidden, const float* __restrict__ bW,
                   const float* __restrict__ bb, float* __restrict__ hbuf_f32,
                   ushort* __restrict__ hbuf_bf) {
  __shared__ float ih[512];
  int b = blockIdx.x, tid = threadIdx.x;
  ih[tid] = init_hidden[b * 512 + tid];
  ih[tid + 256] = init_hidden[b * 512 + 256 + tid];
  __syncthreads();
  for (int rep = 0; rep < 2; ++rep) {
    int j = tid + rep * 256;
    const float4* wr = reinterpret_cast<const float4*>(bW + (size_t)j * 512);
    float s = 0.0f;
    #pragma unroll 4
    for (int k = 0; k < 128; ++k) {
      float4 wv = wr[k];
      s += wv.x * ih[k*4] + wv.y * ih[k*4+1] + wv.z * ih[k*4+2] + wv.w * ih[k*4+3];
    }
    float v = tanhf(s + bb[j]);
    hbuf_f32[b * 512 + j] = v;
    hbuf_bf[b * 512 + j]  = f2bf(v);
  }
}

// ---------------------------------------------------------------- generic GEMM C = A * Bw(bf16)^T + bias
// AMODE: 0 = A f32, 1 = A f32 row-gather, 2 = A bf16.   STATS: emit per-(row,colblock) (max,sumexp).
template<int AMODE, int TANH, int STATS>
__global__ __launch_bounds__(256, 2)
void gemm_bt(const void* __restrict__ Av, const ushort* __restrict__ Bw,
             const float* __restrict__ bias, float* __restrict__ C,
             const int* __restrict__ gidx, float2* __restrict__ partials,
             int N, int K, int PNB) {
  __shared__ __align__(16) char smem[32768];
  __shared__ float pm[128][2], ps[128][2];
  char* smA = smem;
  char* smB = smem + 16384;
  const int tid = threadIdx.x;
  const int w = tid >> 6, l = tid & 63;
  const int mb0 = blockIdx.x * 128, nb0 = blockIdx.y * 128;
  const int msub = (w & 1) * 64, nsub = (w >> 1) * 64;

  f32x4 acc[4][4] = {};
  const int kiters = K >> 6;
  for (int ki = 0; ki < kiters; ++ki) {
    __syncthreads();
    if (AMODE == 2) {
      const ushort* A16 = (const ushort*)Av;
      #pragma unroll
      for (int c = 0; c < 4; ++c) {
        int id = tid + c * 256;
        int row = id >> 3, kc = id & 7;
        uint4 av = *reinterpret_cast<const uint4*>(A16 + (size_t)(mb0 + row) * K + ki * 64 + kc * 8);
        int byte = row * 128 + swz(row, kc);
        *reinterpret_cast<uint4*>(smA + byte) = av;
      }
    } else {
      const float* A32 = (const float*)Av;
      #pragma unroll
      for (int c = 0; c < 8; ++c) {
        int id = tid + c * 256;
        int row = id >> 4, f4 = id & 15;
        int arow = (AMODE == 1) ? gidx[mb0 + row] : (mb0 + row);
        float4 av = *reinterpret_cast<const float4*>(A32 + (size_t)arow * K + ki * 64 + f4 * 4);
        uint32_t lo = (uint32_t)f2bf(av.x) | ((uint32_t)f2bf(av.y) << 16);
        uint32_t hi = (uint32_t)f2bf(av.z) | ((uint32_t)f2bf(av.w) << 16);
        int byte = row * 128 + swz(row, f4 >> 1) + (f4 & 1) * 8;
        *reinterpret_cast<uint2*>(smA + byte) = make_uint2(lo, hi);
      }
    }
    #pragma unroll
    for (int c = 0; c < 4; ++c) {
      int id = tid + c * 256;
      int row = id >> 3, kc = id & 7;
      uint4 bv = *reinterpret_cast<const uint4*>(Bw + (size_t)(nb0 + row) * K + ki * 64 + kc * 8);
      int byte = row * 128 + swz(row, kc);
      *reinterpret_cast<uint4*>(smB + byte) = bv;
    }
    __syncthreads();
    #pragma unroll
    for (int ks = 0; ks < 2; ++ks) {
      bf16x8 af[4], bfr[4];
      #pragma unroll
      for (int i = 0; i < 4; ++i) {
        int row = msub + i * 16 + (l & 15);
        af[i] = *reinterpret_cast<const bf16x8*>(smA + row * 128 + swz(row, ks * 4 + (l >> 4)));
      }
      #pragma unroll
      for (int i = 0; i < 4; ++i) {
        int row = nsub + i * 16 + (l & 15);
        bfr[i] = *reinterpret_cast<const bf16x8*>(smB + row * 128 + swz(row, ks * 4 + (l >> 4)));
      }
      #pragma unroll
      for (int mi = 0; mi < 4; ++mi)
        #pragma unroll
        for (int ni = 0; ni < 4; ++ni)
          acc[mi][ni] = mfma16(af[mi], bfr[ni], acc[mi][ni]);
    }
  }
  // add bias into acc, store, then (optionally) per-row stats
  float bcol[4];
  #pragma unroll
  for (int ni = 0; ni < 4; ++ni)
    bcol[ni] = bias ? bias[nb0 + nsub + ni * 16 + (l & 15)] : 0.0f;
  #pragma unroll
  for (int mi = 0; mi < 4; ++mi) {
    #pragma unroll
    for (int ni = 0; ni < 4; ++ni) {
      int col = nb0 + nsub + ni * 16 + (l & 15);
      #pragma unroll
      for (int j = 0; j < 4; ++j) {
        int row = mb0 + msub + mi * 16 + (l >> 4) * 4 + j;
        float v = acc[mi][ni][j] + bcol[ni];
        acc[mi][ni][j] = v;
        if (TANH) v = tanhf(v);
        C[(size_t)row * N + col] = v;
      }
    }
  }
  if (STATS) {
    #pragma unroll
    for (int mi = 0; mi < 4; ++mi) {
      #pragma unroll
      for (int j = 0; j < 4; ++j) {
        float mx = fmaxf(fmaxf(acc[mi][0][j], acc[mi][1][j]), fmaxf(acc[mi][2][j], acc[mi][3][j]));
        #pragma unroll
        for (int d = 1; d < 16; d <<= 1) mx = fmaxf(mx, __shfl_xor(mx, d));
        float sx = expf(acc[mi][0][j] - mx) + expf(acc[mi][1][j] - mx)
                 + expf(acc[mi][2][j] - mx) + expf(acc[mi][3][j] - mx);
        #pragma unroll
        for (int d = 1; d < 16; d <<= 1) sx += __shfl_xor(sx, d);
        if ((l & 15) == 0) {
          int r = msub + mi * 16 + (l >> 4) * 4 + j;
          pm[r][w >> 1] = mx;
          ps[r][w >> 1] = sx;
        }
      }
    }
    __syncthreads();
    if (tid < 128) {
      float ma = pm[tid][0], mb = pm[tid][1];
      float m = fmaxf(ma, mb);
      float s = ps[tid][0] * expf(ma - m) + ps[tid][1] * expf(mb - m);
      partials[(size_t)(mb0 + tid) * PNB + blockIdx.y] = make_float2(m, s);
    }
  }
}

// ---------------------------------------------------------------- LSTM recurrence (persistent, 32 blocks, flag sync)
__global__ __launch_bounds__(256, 1)
void lstm_rec(const ushort* __restrict__ Whh_bf, const float* __restrict__ gates_x,
              float* __restrict__ hbuf_f32, ushort* __restrict__ hbuf_bf,
              int* __restrict__ flags) {
  __shared__ __align__(16) char h_lds[32 * 1024];   // [32][512] bf16, swizzled rows
  __shared__ float gt[32 * 64];
  __shared__ float c_state[512];
  const int tid = threadIdx.x, w = tid >> 6, l = tid & 63;
  const int blk = blockIdx.x;
  const int gate0 = (w >> 1) * 2;
  const int mtile = (w & 1);

  bf16x8 wf[2][16];
  #pragma unroll
  for (int nt = 0; nt < 2; ++nt) {
    int grow = (gate0 + nt) * 512 + blk * 16 + (l & 15);
    const ushort* base = Whh_bf + (size_t)grow * 512 + (l >> 4) * 8;
    #pragma unroll
    for (int ks = 0; ks < 16; ++ks)
      wf[nt][ks] = *reinterpret_cast<const bf16x8*>(base + ks * 32);
  }

  for (int idx = tid; idx < 512; idx += 256) {
    int b = idx >> 4, cc = idx & 15;
    c_state[idx] = hbuf_f32[b * 512 + blk * 16 + cc];   // c0 = h0
  }

  float gpre[2][4];
  #pragma unroll
  for (int nt = 0; nt < 2; ++nt)
    #pragma unroll
    for (int j = 0; j < 4; ++j) {
      int b = mtile * 16 + (l >> 4) * 4 + j;
      gpre[nt][j] = gates_x[(size_t)b * 2048 + (gate0 + nt) * 512 + blk * 16 + (l & 15)];
    }

  for (int t = 0; t < NTGT; ++t) {
    // stage h_t (bf16) into LDS
    const ushort* hsrc = hbuf_bf + (size_t)t * (32 * 512);
    #pragma unroll
    for (int c = 0; c < 8; ++c) {
      int id = tid + c * 256;
      int row = id >> 6, ch = id & 63;
      uint4 v = *reinterpret_cast<const uint4*>(hsrc + row * 512 + ch * 8);
      *reinterpret_cast<uint4*>(h_lds + row * 1024 + ((ch * 16) ^ ((row & 7) * 16))) = v;
    }
    __syncthreads();

    f32x4 acc[2];
    #pragma unroll
    for (int nt = 0; nt < 2; ++nt)
      #pragma unroll
      for (int j = 0; j < 4; ++j)
        acc[nt][j] = gpre[nt][j];
    #pragma unroll
    for (int ks = 0; ks < 16; ++ks) {
      int row = mtile * 16 + (l & 15);
      bf16x8 af = *reinterpret_cast<const bf16x8*>(
          h_lds + row * 1024 + (((ks * 4 + (l >> 4)) * 16) ^ ((row & 7) * 16)));
      acc[0] = mfma16(af, wf[0][ks], acc[0]);
      acc[1] = mfma16(af, wf[1][ks], acc[1]);
    }
    #pragma unroll
    for (int nt = 0; nt < 2; ++nt)
      #pragma unroll
      for (int j = 0; j < 4; ++j) {
        int b = mtile * 16 + (l >> 4) * 4 + j;
        gt[b * 64 + (gate0 + nt) * 16 + (l & 15)] = acc[nt][j];
      }
    __syncthreads();

    #pragma unroll
    for (int rep = 0; rep < 2; ++rep) {
      int idx = tid + rep * 256;
      int b = idx >> 4, cc = idx & 15;
      float gi = gt[b * 64 + cc],      gf = gt[b * 64 + 16 + cc];
      float gg = gt[b * 64 + 32 + cc], go = gt[b * 64 + 48 + cc];
      float cn = sigmoidf_(gf) * c_state[idx] + sigmoidf_(gi) * tanhf(gg);
      float hn = sigmoidf_(go) * tanhf(cn);
      c_state[idx] = cn;
      size_t o = (size_t)(t + 1) * (32 * 512) + b * 512 + blk * 16 + cc;
      hbuf_f32[o] = hn;   // plain store: only read after kernel end
      __hip_atomic_store(&hbuf_bf[o], f2bf(hn), __ATOMIC_RELAXED, __HIP_MEMORY_SCOPE_AGENT);
    }
    // drain own device-scope stores, block barrier, then publish flag
    asm volatile("s_waitcnt vmcnt(0)" ::: "memory");
    __syncthreads();
    if (tid == 0)
      __hip_atomic_store(&flags[blk * 32], t + 1, __ATOMIC_RELAXED, __HIP_MEMORY_SCOPE_AGENT);

    if (t + 1 < NTGT) {
      // prefetch next step's input gates while others finish
      #pragma unroll
      for (int nt = 0; nt < 2; ++nt)
        #pragma unroll
        for (int j = 0; j < 4; ++j) {
          int b = mtile * 16 + (l >> 4) * 4 + j;
          gpre[nt][j] = gates_x[(size_t)((t + 1) * 32 + b) * 2048 + (gate0 + nt) * 512 + blk * 16 + (l & 15)];
        }
      if (w == 0) {
        int target = t + 1;
        while (true) {
          int f = (l < 32) ? __hip_atomic_load(&flags[l * 32], __ATOMIC_RELAXED, __HIP_MEMORY_SCOPE_AGENT)
                           : target;
          if (__all(f >= target)) break;
          __builtin_amdgcn_s_sleep(1);
        }
        __builtin_amdgcn_fence(__ATOMIC_ACQUIRE, "agent");  // invalidate L1/L2 → fresh h reads
      }
      __syncthreads();
    }
  }
}

// ---------------------------------------------------------------- per-row stats: merge gen partials + copy scores
__global__ __launch_bounds__(256, 2)
void stats_kernel(const float2* __restrict__ partials, const float* __restrict__ hbuf_f32,
                  const float* __restrict__ u_feat, float* __restrict__ ue_out,
                  float4* __restrict__ stats) {
  __shared__ float red[256];
  __shared__ float hl[512];
  __shared__ float up[256];
  int r = blockIdx.x, tid = threadIdx.x;
  int t = r >> 5, b = r & 31;
  float m_i = -3.0e38f, s_i = 0.0f;
  if (tid < 250) { float2 p = partials[(size_t)r * 250 + tid]; m_i = p.x; s_i = p.y; }
  red[tid] = m_i; __syncthreads();
  for (int s = 128; s > 0; s >>= 1) { if (tid < s) red[tid] = fmaxf(red[tid], red[tid + s]); __syncthreads(); }
  float G = red[0]; __syncthreads();
  red[tid] = (tid < 250) ? s_i * expf(m_i - G) : 0.0f; __syncthreads();
  for (int s = 128; s > 0; s >>= 1) { if (tid < s) red[tid] += red[tid + s]; __syncthreads(); }
  float Sg = red[0]; __syncthreads();

  const float* hrow = hbuf_f32 + (size_t)(t + 1) * (32 * 512) + b * 512;
  hl[tid] = hrow[tid]; hl[tid + 256] = hrow[tid + 256];
  __syncthreads();
  {
    int s = tid & 127, half = tid >> 7;
    const float4* uf = reinterpret_cast<const float4*>(u_feat + (size_t)(s * 32 + b) * 512 + half * 256);
    const float* hh = hl + half * 256;
    float p = 0.0f;
    #pragma unroll 4
    for (int k = 0; k < 64; ++k) {
      float4 v = uf[k];
      p += v.x * hh[k*4] + v.y * hh[k*4+1] + v.z * hh[k*4+2] + v.w * hh[k*4+3];
    }
    up[tid] = p;
  }
  __syncthreads();
  float u = 0.0f;
  if (tid < 128) u = up[tid] + up[tid + 128];
  red[tid] = (tid < 128) ? u : -3.0e38f;
  __syncthreads();
  for (int s = 128; s > 0; s >>= 1) { if (tid < s) red[tid] = fmaxf(red[tid], red[tid + s]); __syncthreads(); }
  float umax = red[0]; __syncthreads();
  float uev = 0.0f;
  if (tid < 128) { uev = expf(u - umax); ue_out[(size_t)r * 128 + tid] = uev; }
  red[tid] = (tid < 128) ? uev : 0.0f;
  __syncthreads();
  for (int s = 128; s > 0; s >>= 1) { if (tid < s) red[tid] += red[tid + s]; __syncthreads(); }
  if (tid == 0) {
    float Sue = red[0];
    float M = fmaxf(G, umax);
    float Z = Sg * expf(G - M) + expf(umax - M) * (Sue + (float)VOCAB * 1e-35f);
    stats[r] = make_float4(M, logf(Z), expf(umax - M), 0.0f);
  }
}

// ---------------------------------------------------------------- dense log transform (in place)
__global__ __launch_bounds__(256, 4)
void transform_kernel(float* __restrict__ out, const float4* __restrict__ stats) {
  int r = blockIdx.x, tid = threadIdx.x;
  float4 st = stats[r];
  float M = st.x, logZ = st.y, c0 = st.z * 1e-35f;
  float4* row = reinterpret_cast<float4*>(out + (size_t)r * VOCAB);
  for (int i = 0; i < 32; ++i) {
    int idx = i * 256 + tid;
    if (idx < 8000) {
      float4 x = row[idx];
      x.x = logf(expf(x.x - M) + c0) - logZ;
      x.y = logf(expf(x.y - M) + c0) - logZ;
      x.z = logf(expf(x.z - M) + c0) - logZ;
      x.w = logf(expf(x.w - M) + c0) - logZ;
      row[idx] = x;
    }
  }
}

// ---------------------------------------------------------------- scattered-position fixup
__global__ __launch_bounds__(128, 4)
void fixup_kernel(float* __restrict__ out, const float* __restrict__ hbuf_f32,
                  const float* __restrict__ ue, const int* __restrict__ enc_idxs,
                  const float* __restrict__ outW, const float* __restrict__ outb,
                  const float4* __restrict__ stats) {
  __shared__ float hl[512];
  __shared__ float uel[128];
  __shared__ int il[128];
  int r = blockIdx.x, tid = threadIdx.x;
  int t = r >> 5, b = r & 31;
  const float* hrow = hbuf_f32 + (size_t)(t + 1) * (32 * 512) + b * 512;
  for (int i = tid; i < 512; i += 128) hl[i] = hrow[i];
  uel[tid] = ue[(size_t)r * 128 + tid];
  il[tid]  = enc_idxs[b * NSRC + tid];
  __syncthreads();
  int v = il[tid];
  float scat = 0.0f;
  #pragma unroll 8
  for (int s = 0; s < 128; ++s) scat += (il[s] == v) ? uel[s] : 0.0f;
  const float4* wr = reinterpret_cast<const float4*>(outW + (size_t)v * 512);
  const float4* hf = reinterpret_cast<const float4*>(hl);
  float p = 0.0f;
  #pragma unroll 4
  for (int k = 0; k < 128; ++k) {
    float4 wv = wr[k]; float4 hv = hf[k];
    p += wv.x * hv.x + wv.y * hv.y + wv.z * hv.z + wv.w * hv.w;
  }
  p += outb[v];
  float4 st = stats[r];
  float val = logf(expf(p - st.x) + st.z * (scat + 1e-35f)) - st.y;
  out[(size_t)r * VOCAB + v] = val;
}

// ---------------------------------------------------------------- launch
extern "C" void kernel_launch(void* const* d_in, const int* in_sizes, int n_in,
                              void* d_out, int out_size, void* d_ws, size_t ws_size,
                              hipStream_t stream) {
  (void)in_sizes; (void)n_in; (void)out_size; (void)ws_size;
  const int*   trg      = (const int*)  d_in[0];
  const float* init_h   = (const float*)d_in[1];
  const float* enc_hs   = (const float*)d_in[2];
  const int*   enc_idxs = (const int*)  d_in[3];
  const float* emb      = (const float*)d_in[4];
  const float* W_ih     = (const float*)d_in[5];
  const float* W_hh     = (const float*)d_in[6];
  const float* b_ih     = (const float*)d_in[7];
  const float* b_hh     = (const float*)d_in[8];
  const float* bridge_W = (const float*)d_in[9];
  const float* bridge_b = (const float*)d_in[10];
  const float* out_W    = (const float*)d_in[11];
  const float* out_b    = (const float*)d_in[12];
  const float* copy_W   = (const float*)d_in[13];
  const float* copy_b   = (const float*)d_in[14];
  float* out = (float*)d_out;

  char* ws = (char*)d_ws;
  size_t off = 0;
  auto alloc = [&](size_t bytes) -> char* {
    char* p = ws + off;
    off = (off + bytes + 255) & ~(size_t)255;
    return p;
  };
  ushort* outW_bf  = (ushort*)alloc((size_t)VOCAB * 512 * 2);
  ushort* Wih_bf   = (ushort*)alloc((size_t)2048 * 512 * 2);
  ushort* copyW_bf = (ushort*)alloc((size_t)512 * 512 * 2);
  ushort* Whh_bf   = (ushort*)alloc((size_t)2048 * 512 * 2);
  float*  u_feat   = (float*) alloc((size_t)NSRC * NBAT * 512 * 4);
  float*  gates_x  = (float*) alloc((size_t)NTGT * NBAT * 2048 * 4);
  float*  hbuf_f32 = (float*) alloc((size_t)(NTGT + 1) * NBAT * 512 * 4);
  ushort* hbuf_bf  = (ushort*)alloc((size_t)(NTGT + 1) * NBAT * 512 * 2);
  float*  ue       = (float*) alloc((size_t)2048 * 128 * 4);
  float4* stats    = (float4*)alloc((size_t)2048 * 16);
  int*    tok_in   = (int*)   alloc(2048 * 4);
  float*  bsum     = (float*) alloc(2048 * 4);
  int*    flags    = (int*)   alloc(1024 * 4);
  // partials (4 MB) overlays gates_x: gates_x is dead once lstm_rec completes,
  // and partials is first written by the sg GEMM which runs after lstm_rec.
  float2* partials = (float2*)gates_x;

  init_kernel<<<8, 256, 0, stream>>>(trg, tok_in, b_ih, b_hh, bsum, flags);
  cvt_kernel<<<(VOCAB * 512 / 4 + 255) / 256, 256, 0, stream>>>(out_W, outW_bf, VOCAB * 512 / 4);
  cvt_kernel<<<(2048 * 512 / 4 + 255) / 256, 256, 0, stream>>>(W_ih, Wih_bf, 2048 * 512 / 4);
  cvt_kernel<<<(512 * 512 / 4 + 255) / 256, 256, 0, stream>>>(copy_W, copyW_bf, 512 * 512 / 4);
  cvt_kernel<<<(2048 * 512 / 4 + 255) / 256, 256, 0, stream>>>(W_hh, Whh_bf, 2048 * 512 / 4);

  bridge_kernel<<<32, 256, 0, stream>>>(init_h, bridge_W, bridge_b, hbuf_f32, hbuf_bf);
  // u_feat[s,b,h] = tanh(enc_hs[s,b,:] . copy_W[h,:] + copy_b[h])
  gemm_bt<0, 1, 0><<<dim3(32, 4), 256, 0, stream>>>(enc_hs, copyW_bf, copy_b, u_feat, nullptr, nullptr, 512, 512, 0);
  // gates_x[t,b,:] = emb[tok_in[t,b]] . W_ih^T + b_ih + b_hh
  gemm_bt<1, 0, 0><<<dim3(16, 16), 256, 0, stream>>>(emb, Wih_bf, bsum, gates_x, tok_in, nullptr, 2048, 512, 0);
  lstm_rec<<<32, 256, 0, stream>>>(Whh_bf, gates_x, hbuf_f32, hbuf_bf, flags);
  // sg[t*32+b, v] = h[t,b,:] . out_W[v,:] + out_b[v]  (A read as bf16 directly)
  gemm_bt<2, 0, 1><<<dim3(16, 250), 256, 0, stream>>>(hbuf_bf + 32 * 512, outW_bf, out_b, out, nullptr, partials, VOCAB, 512, 250);
  stats_kernel<<<2048, 256, 0, stream>>>(partials, hbuf_f32, u_feat, ue, stats);
  transform_kernel<<<2048, 256, 0, stream>>>(out, stats);
  fixup_kernel<<<2048, 128, 0, stream>>>(out, hbuf_f32, ue, enc_idxs, out_W, out_b, stats);
}

// Round 3
// 893.265 us; speedup vs baseline: 1.4337x; 1.1253x over previous
//
#include <hip/hip_runtime.h>
#include <stdint.h>

#define VOCAB 32000
#define HID   512
#define NBAT  32
#define NSRC  128
#define NTGT  64

typedef __attribute__((ext_vector_type(8))) __bf16 bf16x8;
typedef __attribute__((ext_vector_type(4))) float  f32x4;

__device__ __forceinline__ ushort f2bf(float f) {
  union { float f; uint32_t u; } v; v.f = f;
  uint32_t u = v.u;
  u += 0x7fffu + ((u >> 16) & 1u);
  return (ushort)(u >> 16);
}

__device__ __forceinline__ float fsig(float x) {
  return __builtin_amdgcn_rcpf(1.0f + __expf(-x));
}
__device__ __forceinline__ float ftanh(float x) {
  return 1.0f - 2.0f * __builtin_amdgcn_rcpf(1.0f + __expf(2.0f * x));
}

__device__ __forceinline__ int swz(int row, int chunk16) {
  return (chunk16 * 16) ^ ((row & 7) * 16);
}

__device__ __forceinline__ f32x4 mfma16(bf16x8 a, bf16x8 b, f32x4 c) {
  return __builtin_amdgcn_mfma_f32_16x16x32_bf16(a, b, c, 0, 0, 0);
}

// coherent (LLC-level) access helpers: sc0 sc1 bypasses non-coherent L1/L2
__device__ __forceinline__ uint4 ld_cohx4(const void* p) {
  uint4 r;
  asm volatile("global_load_dwordx4 %0, %1, off sc0 sc1" : "=v"(r) : "v"(p) : "memory");
  return r;
}
__device__ __forceinline__ int ld_coh32(const void* p) {
  int r;
  asm volatile("global_load_dword %0, %1, off sc0 sc1" : "=v"(r) : "v"(p) : "memory");
  return r;
}
__device__ __forceinline__ void st_coh32(void* p, uint32_t v) {
  asm volatile("global_store_dword %0, %1, off sc0 sc1" :: "v"(p), "v"(v) : "memory");
}

// ---------------------------------------------------------------- utilities
__global__ void init_kernel(const int* __restrict__ trg, int* __restrict__ tok_in,
                            const float* __restrict__ b_ih, const float* __restrict__ b_hh,
                            float* __restrict__ bsum, int* __restrict__ flags) {
  int i = blockIdx.x * 256 + threadIdx.x;
  if (i < 2048) {
    int t = i >> 5, b = i & 31;
    tok_in[i] = (t == 0) ? 0 : trg[b * NTGT + (t - 1)];
    bsum[i] = b_ih[i] + b_hh[i];
  }
  if (i < 1024) flags[i] = 0;   // 32 flags, one per 128B line
}

__global__ void cvt_kernel(const float* __restrict__ src, ushort* __restrict__ dst, int n4) {
  int i = blockIdx.x * 256 + threadIdx.x;
  if (i < n4) {
    float4 v = reinterpret_cast<const float4*>(src)[i];
    ushort4 o;
    o.x = f2bf(v.x); o.y = f2bf(v.y); o.z = f2bf(v.z); o.w = f2bf(v.w);
    reinterpret_cast<ushort4*>(dst)[i] = o;
  }
}

// ---------------------------------------------------------------- bridge
__global__ __launch_bounds__(256, 2)
void bridge_kernel(const float* __restrict__ init_hidden, const float* __restrict__ bW,
                   const float* __restrict__ bb, float* __restrict__ h0_f32,
                   ushort* __restrict__ hbuf_bf) {
  __shared__ float ih[512];
  int b = blockIdx.x, tid = threadIdx.x;
  ih[tid] = init_hidden[b * 512 + tid];
  ih[tid + 256] = init_hidden[b * 512 + 256 + tid];
  __syncthreads();
  for (int rep = 0; rep < 2; ++rep) {
    int j = tid + rep * 256;
    const float4* wr = reinterpret_cast<const float4*>(bW + (size_t)j * 512);
    float s = 0.0f;
    #pragma unroll 4
    for (int k = 0; k < 128; ++k) {
      float4 wv = wr[k];
      s += wv.x * ih[k*4] + wv.y * ih[k*4+1] + wv.z * ih[k*4+2] + wv.w * ih[k*4+3];
    }
    float v = tanhf(s + bb[j]);
    h0_f32[b * 512 + j] = v;
    hbuf_bf[b * 512 + j] = f2bf(v);
  }
}

// ---------------------------------------------------------------- generic GEMM C = A * Bw(bf16)^T + bias
// AMODE: 0 = A f32, 1 = A f32 row-gather, 2 = A bf16.  STATS: per-(row,colblock) (max,sumexp).
// OUT16: store C as bf16. Grid is 1-D (GX*GY) with bijective XCD swizzle.
template<int GX, int AMODE, int TANH, int STATS, int OUT16>
__global__ __launch_bounds__(256, 2)
void gemm_bt(const void* __restrict__ Av, const ushort* __restrict__ Bw,
             const float* __restrict__ bias, void* __restrict__ Cv,
             const int* __restrict__ gidx, float2* __restrict__ partials,
             int N, int K, int PNB) {
  __shared__ __align__(16) char smem[32768];
  __shared__ float pm[128][2], ps[128][2];
  char* smA = smem;
  char* smB = smem + 16384;
  const int tid = threadIdx.x;
  const int w = tid >> 6, l = tid & 63;
  // bijective XCD swizzle (m204): each XCD gets a contiguous chunk of tiles
  const int nblk = gridDim.x;
  const int q = nblk >> 3, rr = nblk & 7;
  const int xcd = blockIdx.x & 7, pos = blockIdx.x >> 3;
  const int sw = (xcd < rr ? xcd * (q + 1) : rr * (q + 1) + (xcd - rr) * q) + pos;
  const int mb0 = (sw % GX) * 128, byc = sw / GX, nb0 = byc * 128;
  const int msub = (w & 1) * 64, nsub = (w >> 1) * 64;

  f32x4 acc[4][4] = {};
  const int kiters = K >> 6;
  for (int ki = 0; ki < kiters; ++ki) {
    __syncthreads();
    if (AMODE == 2) {
      const ushort* A16 = (const ushort*)Av;
      #pragma unroll
      for (int c = 0; c < 4; ++c) {
        int id = tid + c * 256;
        int row = id >> 3, kc = id & 7;
        uint4 av = *reinterpret_cast<const uint4*>(A16 + (size_t)(mb0 + row) * K + ki * 64 + kc * 8);
        *reinterpret_cast<uint4*>(smA + row * 128 + swz(row, kc)) = av;
      }
    } else {
      const float* A32 = (const float*)Av;
      #pragma unroll
      for (int c = 0; c < 8; ++c) {
        int id = tid + c * 256;
        int row = id >> 4, f4 = id & 15;
        int arow = (AMODE == 1) ? gidx[mb0 + row] : (mb0 + row);
        float4 av = *reinterpret_cast<const float4*>(A32 + (size_t)arow * K + ki * 64 + f4 * 4);
        uint32_t lo = (uint32_t)f2bf(av.x) | ((uint32_t)f2bf(av.y) << 16);
        uint32_t hi = (uint32_t)f2bf(av.z) | ((uint32_t)f2bf(av.w) << 16);
        int byte = row * 128 + swz(row, f4 >> 1) + (f4 & 1) * 8;
        *reinterpret_cast<uint2*>(smA + byte) = make_uint2(lo, hi);
      }
    }
    #pragma unroll
    for (int c = 0; c < 4; ++c) {
      int id = tid + c * 256;
      int row = id >> 3, kc = id & 7;
      uint4 bv = *reinterpret_cast<const uint4*>(Bw + (size_t)(nb0 + row) * K + ki * 64 + kc * 8);
      *reinterpret_cast<uint4*>(smB + row * 128 + swz(row, kc)) = bv;
    }
    __syncthreads();
    #pragma unroll
    for (int ks = 0; ks < 2; ++ks) {
      bf16x8 af[4], bfr[4];
      #pragma unroll
      for (int i = 0; i < 4; ++i) {
        int row = msub + i * 16 + (l & 15);
        af[i] = *reinterpret_cast<const bf16x8*>(smA + row * 128 + swz(row, ks * 4 + (l >> 4)));
      }
      #pragma unroll
      for (int i = 0; i < 4; ++i) {
        int row = nsub + i * 16 + (l & 15);
        bfr[i] = *reinterpret_cast<const bf16x8*>(smB + row * 128 + swz(row, ks * 4 + (l >> 4)));
      }
      #pragma unroll
      for (int mi = 0; mi < 4; ++mi)
        #pragma unroll
        for (int ni = 0; ni < 4; ++ni)
          acc[mi][ni] = mfma16(af[mi], bfr[ni], acc[mi][ni]);
    }
  }
  float bcol[4];
  #pragma unroll
  for (int ni = 0; ni < 4; ++ni)
    bcol[ni] = bias ? bias[nb0 + nsub + ni * 16 + (l & 15)] : 0.0f;
  #pragma unroll
  for (int mi = 0; mi < 4; ++mi) {
    #pragma unroll
    for (int ni = 0; ni < 4; ++ni) {
      int col = nb0 + nsub + ni * 16 + (l & 15);
      #pragma unroll
      for (int j = 0; j < 4; ++j) {
        int row = mb0 + msub + mi * 16 + (l >> 4) * 4 + j;
        float v = acc[mi][ni][j] + bcol[ni];
        acc[mi][ni][j] = v;
        if (TANH) v = tanhf(v);
        if (OUT16) ((ushort*)Cv)[(size_t)row * N + col] = f2bf(v);
        else       ((float*)Cv)[(size_t)row * N + col] = v;
      }
    }
  }
  if (STATS) {
    #pragma unroll
    for (int mi = 0; mi < 4; ++mi) {
      #pragma unroll
      for (int j = 0; j < 4; ++j) {
        float mx = fmaxf(fmaxf(acc[mi][0][j], acc[mi][1][j]), fmaxf(acc[mi][2][j], acc[mi][3][j]));
        #pragma unroll
        for (int d = 1; d < 16; d <<= 1) mx = fmaxf(mx, __shfl_xor(mx, d));
        float sx = __expf(acc[mi][0][j] - mx) + __expf(acc[mi][1][j] - mx)
                 + __expf(acc[mi][2][j] - mx) + __expf(acc[mi][3][j] - mx);
        #pragma unroll
        for (int d = 1; d < 16; d <<= 1) sx += __shfl_xor(sx, d);
        if ((l & 15) == 0) {
          int r = msub + mi * 16 + (l >> 4) * 4 + j;
          pm[r][w >> 1] = mx;
          ps[r][w >> 1] = sx;
        }
      }
    }
    __syncthreads();
    if (tid < 128) {
      float ma = pm[tid][0], mb = pm[tid][1];
      float m = fmaxf(ma, mb);
      float s = ps[tid][0] * __expf(ma - m) + ps[tid][1] * __expf(mb - m);
      partials[(size_t)(mb0 + tid) * PNB + byc] = make_float2(m, s);
    }
  }
}

// ---------------------------------------------------------------- LSTM recurrence (persistent, 32 blocks, coherent flag sync)
__global__ __launch_bounds__(256, 1)
void lstm_rec(const ushort* __restrict__ Whh_bf, const float* __restrict__ gates_x,
              const float* __restrict__ h0_f32, ushort* __restrict__ hbuf_bf,
              int* __restrict__ flags) {
  __shared__ __align__(16) char h_lds[32 * 1024];
  __shared__ float gt[32 * 64];
  __shared__ float2 c_state[256];
  const int tid = threadIdx.x, w = tid >> 6, l = tid & 63;
  const int blk = blockIdx.x;
  const int gate0 = (w >> 1) * 2;
  const int mtile = (w & 1);

  bf16x8 wf[2][16];
  #pragma unroll
  for (int nt = 0; nt < 2; ++nt) {
    int grow = (gate0 + nt) * 512 + blk * 16 + (l & 15);
    const ushort* base = Whh_bf + (size_t)grow * 512 + (l >> 4) * 8;
    #pragma unroll
    for (int ks = 0; ks < 16; ++ks)
      wf[nt][ks] = *reinterpret_cast<const bf16x8*>(base + ks * 32);
  }

  {
    int b = tid >> 3, c2 = (tid & 7) * 2;
    c_state[tid] = *reinterpret_cast<const float2*>(h0_f32 + b * 512 + blk * 16 + c2);
  }

  float gpre[2][4];
  #pragma unroll
  for (int nt = 0; nt < 2; ++nt)
    #pragma unroll
    for (int j = 0; j < 4; ++j) {
      int b = mtile * 16 + (l >> 4) * 4 + j;
      gpre[nt][j] = gates_x[(size_t)b * 2048 + (gate0 + nt) * 512 + blk * 16 + (l & 15)];
    }

  for (int t = 0; t < NTGT; ++t) {
    // stage h_t into LDS via coherent 16B loads (no cache-invalidate fence needed)
    const ushort* hsrc = hbuf_bf + (size_t)t * (32 * 512);
    uint4 hv[8];
    #pragma unroll
    for (int c = 0; c < 8; ++c) {
      int id = tid + c * 256;
      hv[c] = ld_cohx4(hsrc + (id >> 6) * 512 + (id & 63) * 8);
    }
    asm volatile("s_waitcnt vmcnt(0)" ::: "memory");
    __builtin_amdgcn_sched_barrier(0);
    #pragma unroll
    for (int c = 0; c < 8; ++c) {
      int id = tid + c * 256;
      int row = id >> 6, ch = id & 63;
      *reinterpret_cast<uint4*>(h_lds + row * 1024 + ((ch * 16) ^ ((row & 7) * 16))) = hv[c];
    }
    __syncthreads();

    f32x4 acc[2];
    #pragma unroll
    for (int nt = 0; nt < 2; ++nt)
      #pragma unroll
      for (int j = 0; j < 4; ++j)
        acc[nt][j] = gpre[nt][j];
    #pragma unroll
    for (int ks = 0; ks < 16; ++ks) {
      int row = mtile * 16 + (l & 15);
      bf16x8 af = *reinterpret_cast<const bf16x8*>(
          h_lds + row * 1024 + (((ks * 4 + (l >> 4)) * 16) ^ ((row & 7) * 16)));
      acc[0] = mfma16(af, wf[0][ks], acc[0]);
      acc[1] = mfma16(af, wf[1][ks], acc[1]);
    }
    #pragma unroll
    for (int nt = 0; nt < 2; ++nt)
      #pragma unroll
      for (int j = 0; j < 4; ++j) {
        int b = mtile * 16 + (l >> 4) * 4 + j;
        gt[b * 64 + (gate0 + nt) * 16 + (l & 15)] = acc[nt][j];
      }
    __syncthreads();

    {
      int b = tid >> 3, c2 = (tid & 7) * 2;
      const float2* g2 = reinterpret_cast<const float2*>(gt);
      float2 gi = g2[(b * 64 +  0 + c2) >> 1];
      float2 gf = g2[(b * 64 + 16 + c2) >> 1];
      float2 gg = g2[(b * 64 + 32 + c2) >> 1];
      float2 go = g2[(b * 64 + 48 + c2) >> 1];
      float2 cs = c_state[tid];
      float cn0 = fsig(gf.x) * cs.x + fsig(gi.x) * ftanh(gg.x);
      float cn1 = fsig(gf.y) * cs.y + fsig(gi.y) * ftanh(gg.y);
      float hn0 = fsig(go.x) * ftanh(cn0);
      float hn1 = fsig(go.y) * ftanh(cn1);
      c_state[tid] = make_float2(cn0, cn1);
      uint32_t pk = (uint32_t)f2bf(hn0) | ((uint32_t)f2bf(hn1) << 16);
      st_coh32(hbuf_bf + (size_t)(t + 1) * (32 * 512) + b * 512 + blk * 16 + c2, pk);
    }
    asm volatile("s_waitcnt vmcnt(0)" ::: "memory");  // own coherent stores reached LLC
    __syncthreads();                                  // all waves in block drained
    if (tid == 0) st_coh32(flags + blk * 32, (uint32_t)(t + 1));

    if (t + 1 < NTGT) {
      #pragma unroll
      for (int nt = 0; nt < 2; ++nt)
        #pragma unroll
        for (int j = 0; j < 4; ++j) {
          int b = mtile * 16 + (l >> 4) * 4 + j;
          gpre[nt][j] = gates_x[(size_t)((t + 1) * 32 + b) * 2048 + (gate0 + nt) * 512 + blk * 16 + (l & 15)];
        }
      if (w == 0) {
        int target = t + 1;
        const int* fp = flags + (l & 31) * 32;
        while (true) {
          int f = ld_coh32(fp);
          asm volatile("s_waitcnt vmcnt(0)" ::: "memory");
          if (__all(f >= target)) break;
          __builtin_amdgcn_s_sleep(1);
        }
      }
      __syncthreads();
    }
  }
}

// ---------------------------------------------------------------- fused copy-score + gather-score GEMM (per batch b)
// U[t*32+b][s] = h[t,b,:].u_feat[b,s,:]      P[t*32+b][s] = h[t,b,:].outW[idx[b,s],:] + out_b[idx]
__global__ __launch_bounds__(256, 2)
void copy_kernel(const ushort* __restrict__ hbuf_bf, const ushort* __restrict__ u_feat_bf,
                 const ushort* __restrict__ outW_bf, const float* __restrict__ out_b,
                 const int* __restrict__ enc_idxs, float* __restrict__ U, float* __restrict__ P) {
  __shared__ int il[128];
  __shared__ float ob[128];
  int b = blockIdx.x, tid = threadIdx.x, w = tid >> 6, l = tid & 63;
  if (tid < 128) { int v = enc_idxs[b * 128 + tid]; il[tid] = v; ob[tid] = out_b[v]; }
  __syncthreads();
  f32x4 aU[8] = {}, aP[8] = {};
  const int t_lane = w * 16 + (l & 15);
  const ushort* arow = hbuf_bf + ((size_t)(t_lane + 1) * 32 + b) * 512 + (l >> 4) * 8;
  for (int ks = 0; ks < 16; ++ks) {
    bf16x8 af = *reinterpret_cast<const bf16x8*>(arow + ks * 32);
    #pragma unroll
    for (int ni = 0; ni < 8; ++ni) {
      int s = ni * 16 + (l & 15);
      bf16x8 bu = *reinterpret_cast<const bf16x8*>(u_feat_bf + ((size_t)s * 32 + b) * 512 + ks * 32 + (l >> 4) * 8);
      aU[ni] = mfma16(af, bu, aU[ni]);
      bf16x8 bp = *reinterpret_cast<const bf16x8*>(outW_bf + (size_t)il[s] * 512 + ks * 32 + (l >> 4) * 8);
      aP[ni] = mfma16(af, bp, aP[ni]);
    }
  }
  #pragma unroll
  for (int ni = 0; ni < 8; ++ni) {
    int s = ni * 16 + (l & 15);
    #pragma unroll
    for (int j = 0; j < 4; ++j) {
      int t = w * 16 + (l >> 4) * 4 + j;
      size_t r = (size_t)(t * 32 + b) * 128 + s;
      U[r] = aU[ni][j];
      P[r] = aP[ni][j] + ob[s];
    }
  }
}

// ---------------------------------------------------------------- per-row stats merge
__global__ __launch_bounds__(256, 2)
void stats_kernel(const float2* __restrict__ partials, const float* __restrict__ U,
                  float4* __restrict__ stats) {
  __shared__ float red[256];
  int r = blockIdx.x, tid = threadIdx.x;
  float m_i = -3.0e38f, s_i = 0.0f;
  if (tid < 250) { float2 p = partials[(size_t)r * 250 + tid]; m_i = p.x; s_i = p.y; }
  red[tid] = m_i; __syncthreads();
  for (int s = 128; s > 0; s >>= 1) { if (tid < s) red[tid] = fmaxf(red[tid], red[tid + s]); __syncthreads(); }
  float G = red[0]; __syncthreads();
  red[tid] = (tid < 250) ? s_i * __expf(m_i - G) : 0.0f; __syncthreads();
  for (int s = 128; s > 0; s >>= 1) { if (tid < s) red[tid] += red[tid + s]; __syncthreads(); }
  float Sg = red[0]; __syncthreads();

  float u = (tid < 128) ? U[(size_t)r * 128 + tid] : -3.0e38f;
  red[tid] = u; __syncthreads();
  for (int s = 128; s > 0; s >>= 1) { if (tid < s) red[tid] = fmaxf(red[tid], red[tid + s]); __syncthreads(); }
  float umax = red[0]; __syncthreads();
  red[tid] = (tid < 128) ? __expf(u - umax) : 0.0f; __syncthreads();
  for (int s = 128; s > 0; s >>= 1) { if (tid < s) red[tid] += red[tid + s]; __syncthreads(); }
  if (tid == 0) {
    float Sue = red[0];
    float M = fmaxf(G, umax);
    float eum = __expf(umax - M);
    float Z = Sg * __expf(G - M) + eum * (Sue + (float)VOCAB * 1e-35f);
    stats[r] = make_float4(M, logf(Z), eum, umax);
  }
}

// ---------------------------------------------------------------- dense affine shift (in place): out = sg - (M + logZ)
__global__ __launch_bounds__(256, 4)
void transform_kernel(float* __restrict__ out, const float4* __restrict__ stats) {
  int r = blockIdx.x, tid = threadIdx.x;
  float4 st = stats[r];
  float sh = st.x + st.y;
  float4* row = reinterpret_cast<float4*>(out + (size_t)r * VOCAB);
  for (int i = 0; i < 32; ++i) {
    int idx = i * 256 + tid;
    if (idx < 8000) {
      float4 x = row[idx];
      x.x -= sh; x.y -= sh; x.z -= sh; x.w -= sh;
      row[idx] = x;
    }
  }
}

// ---------------------------------------------------------------- scattered-position exact overwrite
__global__ __launch_bounds__(128, 4)
void scatter_kernel(float* __restrict__ out, const float* __restrict__ U,
                    const float* __restrict__ P, const int* __restrict__ enc_idxs,
                    const float4* __restrict__ stats) {
  __shared__ float uel[128];
  __shared__ int il[128];
  int r = blockIdx.x, tid = threadIdx.x, b = r & 31;
  float4 st = stats[r];
  float M = st.x, logZ = st.y, eum = st.z, umax = st.w;
  int v = enc_idxs[b * NSRC + tid]; il[tid] = v;
  float uev = __expf(U[(size_t)r * 128 + tid] - umax);
  uel[tid] = uev;
  __syncthreads();
  float scat = 0.0f;
  #pragma unroll 8
  for (int s = 0; s < 128; ++s) scat += (il[s] == v) ? uel[s] : 0.0f;
  float p = P[(size_t)r * 128 + tid];
  float val = logf(expf(p - M) + eum * (scat + 1e-35f)) - logZ;
  out[(size_t)r * VOCAB + v] = val;
}

// ---------------------------------------------------------------- launch
extern "C" void kernel_launch(void* const* d_in, const int* in_sizes, int n_in,
                              void* d_out, int out_size, void* d_ws, size_t ws_size,
                              hipStream_t stream) {
  (void)in_sizes; (void)n_in; (void)out_size; (void)ws_size;
  const int*   trg      = (const int*)  d_in[0];
  const float* init_h   = (const float*)d_in[1];
  const float* enc_hs   = (const float*)d_in[2];
  const int*   enc_idxs = (const int*)  d_in[3];
  const float* emb      = (const float*)d_in[4];
  const float* W_ih     = (const float*)d_in[5];
  const float* W_hh     = (const float*)d_in[6];
  const float* b_ih     = (const float*)d_in[7];
  const float* b_hh     = (const float*)d_in[8];
  const float* bridge_W = (const float*)d_in[9];
  const float* bridge_b = (const float*)d_in[10];
  const float* out_W    = (const float*)d_in[11];
  const float* out_b    = (const float*)d_in[12];
  const float* copy_W   = (const float*)d_in[13];
  const float* copy_b   = (const float*)d_in[14];
  float* out = (float*)d_out;

  char* ws = (char*)d_ws;
  size_t off = 0;
  auto alloc = [&](size_t bytes) -> char* {
    char* p = ws + off;
    off = (off + bytes + 255) & ~(size_t)255;
    return p;
  };
  ushort* outW_bf  = (ushort*)alloc((size_t)VOCAB * 512 * 2);
  ushort* Wih_bf   = (ushort*)alloc((size_t)2048 * 512 * 2);
  ushort* copyW_bf = (ushort*)alloc((size_t)512 * 512 * 2);
  ushort* Whh_bf   = (ushort*)alloc((size_t)2048 * 512 * 2);
  ushort* u_feat_bf= (ushort*)alloc((size_t)NSRC * NBAT * 512 * 2);
  float*  gates_x  = (float*) alloc((size_t)NTGT * NBAT * 2048 * 4);
  float*  h0_f32   = (float*) alloc((size_t)NBAT * 512 * 4);
  ushort* hbuf_bf  = (ushort*)alloc((size_t)(NTGT + 1) * NBAT * 512 * 2);
  float*  U        = (float*) alloc((size_t)2048 * 128 * 4);
  float*  P        = (float*) alloc((size_t)2048 * 128 * 4);
  float4* stats    = (float4*)alloc((size_t)2048 * 16);
  int*    tok_in   = (int*)   alloc(2048 * 4);
  float*  bsum     = (float*) alloc(2048 * 4);
  int*    flags    = (int*)   alloc(1024 * 4);
  float2* partials = (float2*)gates_x;   // overlay: gates_x dead after lstm_rec

  init_kernel<<<8, 256, 0, stream>>>(trg, tok_in, b_ih, b_hh, bsum, flags);
  cvt_kernel<<<(VOCAB * 512 / 4 + 255) / 256, 256, 0, stream>>>(out_W, outW_bf, VOCAB * 512 / 4);
  cvt_kernel<<<(2048 * 512 / 4 + 255) / 256, 256, 0, stream>>>(W_ih, Wih_bf, 2048 * 512 / 4);
  cvt_kernel<<<(512 * 512 / 4 + 255) / 256, 256, 0, stream>>>(copy_W, copyW_bf, 512 * 512 / 4);
  cvt_kernel<<<(2048 * 512 / 4 + 255) / 256, 256, 0, stream>>>(W_hh, Whh_bf, 2048 * 512 / 4);

  bridge_kernel<<<32, 256, 0, stream>>>(init_h, bridge_W, bridge_b, h0_f32, hbuf_bf);
  gemm_bt<32, 0, 1, 0, 1><<<128, 256, 0, stream>>>(enc_hs, copyW_bf, copy_b, u_feat_bf, nullptr, nullptr, 512, 512, 0);
  gemm_bt<16, 1, 0, 0, 0><<<256, 256, 0, stream>>>(emb, Wih_bf, bsum, gates_x, tok_in, nullptr, 2048, 512, 0);
  lstm_rec<<<32, 256, 0, stream>>>(Whh_bf, gates_x, h0_f32, hbuf_bf, flags);
  gemm_bt<16, 2, 0, 1, 0><<<4000, 256, 0, stream>>>(hbuf_bf + 32 * 512, outW_bf, out_b, out, nullptr, partials, VOCAB, 512, 250);
  copy_kernel<<<32, 256, 0, stream>>>(hbuf_bf, u_feat_bf, outW_bf, out_b, enc_idxs, U, P);
  stats_kernel<<<2048, 256, 0, stream>>>(partials, U, stats);
  transform_kernel<<<2048, 256, 0, stream>>>(out, stats);
  scatter_kernel<<<2048, 128, 0, stream>>>(out, U, P, enc_idxs, stats);
}